// Round 10
// baseline (390.608 us; speedup 1.0000x reference)
//
#include <hip/hip_runtime.h>

typedef unsigned short u16;
typedef unsigned int   u32;
typedef unsigned char  u8;
typedef __attribute__((ext_vector_type(8))) short bf16x8;
typedef __attribute__((ext_vector_type(4))) float f32x4;

#define N_P 200000
#define N_A 100000
#define DD  64
#define HH  32
#define NE  1000000
#define NBP 782          // (N_P+255)/256
#define NBA 391          // (N_A+255)/256
#define NB_T1 1173       // NBP+NBA
#define TSPLIT 500       // t1 blocks in pA; rest in pB
#define NB4K 245         // ceil(NE/4096)
#define NCB 196          // coarse buckets per relation (paper: 1024-wide, author: 512-wide)
#define P4CAP 8192       // max edges per coarse bucket (mean 5102, sigma ~71)
#define NB_P16 12500     // N_P/16 (exact)
#define NB_A16 6250      // N_A/16 (exact)
#define NB4K3 735        // 3*NB4K

// ---------- bf16 helpers ----------
__device__ inline float bf2f(u16 u) { return __uint_as_float(((u32)u) << 16); }
__device__ inline u16 f2bf(float f) {
    u32 u = __float_as_uint(f);
    u += 0x7fffu + ((u >> 16) & 1u);
    return (u16)(u >> 16);
}
__device__ inline float lo_f(u32 m) { return __uint_as_float(m << 16); }
__device__ inline float hi_f(u32 m) { return __uint_as_float(m & 0xffff0000u); }
// HW packed f32->2xbf16 (RNE), 1 instr
__device__ inline u32 cvtpk(float a, float b) {
    u32 r;
    asm("v_cvt_pk_bf16_f32 %0, %1, %2" : "=v"(r) : "v"(a), "v"(b));
    return r;
}

// ---------- dual-stream gather-sum (R8 form: low-VGPR, at random-line roofline) ----------
__device__ inline void gseg_dual(
    const u16* __restrict__ yA, const int* __restrict__ bkA, int s0, int e0,
    const u16* __restrict__ yB, const int* __restrict__ bkB, int s1, int e1,
    int lane, float& axo, float& ayo, float& bxo, float& byo) {
    float ax = 0.f, ay = 0.f, bx = 0.f, by = 0.f;
    int lastA = min(max(e0 - 1, s0), NE - 1);
    int lastB = min(max(e1 - 1, s1), NE - 1);
    for (int j0 = s0, j1 = s1; (j0 < e0) || (j1 < e1); j0 += 8, j1 += 8) {
        int ia[8], ib[8];
#pragma unroll
        for (int i = 0; i < 8; ++i) ia[i] = bkA[min(j0 + i, lastA)];
#pragma unroll
        for (int i = 0; i < 8; ++i) ib[i] = bkB[min(j1 + i, lastB)];
        u32 ma[8], mb[8];
#pragma unroll
        for (int i = 0; i < 8; ++i)
            ma[i] = *(const u32*)(yA + (size_t)(u32)ia[i] + lane * 2);
#pragma unroll
        for (int i = 0; i < 8; ++i)
            mb[i] = *(const u32*)(yB + (size_t)(u32)ib[i] + lane * 2);
#pragma unroll
        for (int i = 0; i < 8; ++i) {
            u32 va = (j0 + i < e0) ? ma[i] : 0u;
            ax += lo_f(va); ay += hi_f(va);
        }
#pragma unroll
        for (int i = 0; i < 8; ++i) {
            u32 vb = (j1 + i < e1) ? mb[i] : 0u;
            bx += lo_f(vb); by += hi_f(vb);
        }
    }
    axo = ax; ayo = ay; bxo = bx; byo = by;
}

// ---------- t1 body: MFMA transforms, barrier-free (per-wave private Cs) ----------
__device__ void t1_body(int bx, float* Cs,
    const float* __restrict__ xp, const float* __restrict__ xa,
    const u16* __restrict__ wt1h, const u16* __restrict__ wt1l,
    const float* __restrict__ b1s, const float* __restrict__ b1r,
    u16* __restrict__ y_pc, u16* __restrict__ y_pr, u16* __restrict__ y_aw,
    u16* __restrict__ hb_p, u16* __restrict__ hb_a) {
    int t = threadIdx.x, w = t >> 6, l = t & 63;
    int lm = l & 15, lk = l >> 4;
    bool paper = bx < NBP;
    int row0 = (paper ? bx : bx - NBP) * 256;
    const float* x = paper ? xp : xa;
    int NROW = paper ? N_P : N_A;
    int nv = min(256, NROW - row0);
    bf16x8 xh[4][2], xl[4][2];
#pragma unroll
    for (int i = 0; i < 4; ++i) {
        int rowg = min(row0 + w * 64 + i * 16 + lm, NROW - 1);
        const float* rp = x + (size_t)rowg * DD + lk * 8;
#pragma unroll
        for (int kc = 0; kc < 2; ++kc) {
            float4 a = *(const float4*)(rp + kc * 32);
            float4 b = *(const float4*)(rp + kc * 32 + 4);
            float f[8] = {a.x, a.y, a.z, a.w, b.x, b.y, b.z, b.w};
            union { u32 u[4]; bf16x8 v; } H, L;
#pragma unroll
            for (int j = 0; j < 4; ++j) {
                u32 u0 = __float_as_uint(f[2 * j]);
                u32 u1 = __float_as_uint(f[2 * j + 1]);
                u32 m0 = u0 & 0xffff0000u;
                u32 m1 = u1 & 0xffff0000u;
                H.u[j] = (u0 >> 16) | m1;
                float l0 = f[2 * j]     - __uint_as_float(m0);
                float l1 = f[2 * j + 1] - __uint_as_float(m1);
                L.u[j] = cvtpk(l0, l1);
            }
            xh[i][kc] = H.v; xl[i][kc] = L.v;
        }
    }
    int nw = paper ? 3 : 2;
#pragma unroll 1
    for (int iw = 0; iw < nw; ++iw) {
        int mat = paper ? iw : (3 + iw);
        const u16* Wh = wt1h + mat * 2048;
        const u16* Wl = wt1l + mat * 2048;
        bf16x8 Bh[2][2], Bl[2][2];
#pragma unroll
        for (int ct = 0; ct < 2; ++ct)
#pragma unroll
            for (int kc = 0; kc < 2; ++kc) {
                int off = (ct * 16 + lm) * 64 + kc * 32 + lk * 8;
                Bh[ct][kc] = *(const bf16x8*)(Wh + off);
                Bl[ct][kc] = *(const bf16x8*)(Wl + off);
            }
        float bv[2] = {0.f, 0.f};
        if (paper && iw == 2)  { bv[0] = b1s[lm]; bv[1] = b1s[16 + lm]; }
        if (!paper && iw == 1) { bv[0] = b1r[lm]; bv[1] = b1r[16 + lm]; }
#pragma unroll
        for (int i = 0; i < 4; ++i) {
#pragma unroll
            for (int ct = 0; ct < 2; ++ct) {
                f32x4 acc = {bv[ct], bv[ct], bv[ct], bv[ct]};
                acc = __builtin_amdgcn_mfma_f32_16x16x32_bf16(xh[i][0], Bh[ct][0], acc, 0, 0, 0);
                acc = __builtin_amdgcn_mfma_f32_16x16x32_bf16(xh[i][1], Bh[ct][1], acc, 0, 0, 0);
                acc = __builtin_amdgcn_mfma_f32_16x16x32_bf16(xl[i][0], Bh[ct][0], acc, 0, 0, 0);
                acc = __builtin_amdgcn_mfma_f32_16x16x32_bf16(xl[i][1], Bh[ct][1], acc, 0, 0, 0);
                acc = __builtin_amdgcn_mfma_f32_16x16x32_bf16(xh[i][0], Bl[ct][0], acc, 0, 0, 0);
                acc = __builtin_amdgcn_mfma_f32_16x16x32_bf16(xh[i][1], Bl[ct][1], acc, 0, 0, 0);
                int rbase = w * 64 + i * 16 + lk * 4;
#pragma unroll
                for (int r = 0; r < 4; ++r)
                    Cs[(rbase + r) * 34 + ct * 16 + lm] = acc[r];
            }
        }
        asm volatile("s_waitcnt lgkmcnt(0)" ::: "memory");
        u16* outp;
        if (paper) outp = (iw == 0) ? y_pc : (iw == 1) ? y_pr : hb_p;
        else       outp = (iw == 0) ? y_aw : hb_a;
        u32* g = (u32*)(outp + (size_t)row0 * HH);
#pragma unroll
        for (int p = 0; p < 4; ++p) {
            int j = p * 64 + l;
            int rl = w * 64 + (j >> 2);
            if (rl < nv) {
                const float* q = Cs + rl * 34 + (j & 3) * 8;
                u32 o[4];
#pragma unroll
                for (int jj = 0; jj < 4; ++jj)
                    o[jj] = cvtpk(q[2 * jj], q[2 * jj + 1]);
                *(uint4*)(g + ((size_t)w * 256 + j) * 4) = make_uint4(o[0], o[1], o[2], o[3]);
            }
        }
        asm volatile("" ::: "memory");
    }
}

// ---------- FUSED: prep_w (blocks 0..7) + p1 histogram (blocks 8..742) ----------
__global__ __launch_bounds__(256) void prep1_k(
    const float* __restrict__ W1lc, const float* __restrict__ W1lr,
    const float* __restrict__ W1rc, const float* __restrict__ W1rw,
    const float* __restrict__ W1lw, const float* __restrict__ W1rr,
    const float* __restrict__ W2lc, const float* __restrict__ W2rc,
    const float* __restrict__ W2rw, const float* __restrict__ W2lw,
    const float* __restrict__ b1c, const float* __restrict__ b1w,
    const float* __restrict__ b2c, const float* __restrict__ b2w,
    u16* __restrict__ wt1h, u16* __restrict__ wt1l,
    u16* __restrict__ wt2h, u16* __restrict__ wt2l,
    float* __restrict__ b1s, float* __restrict__ b2s,
    const int* __restrict__ cd, const int* __restrict__ wd, const int* __restrict__ rd,
    int* __restrict__ gsizes) {
    __shared__ int cnt[256];
    int t = threadIdx.x;
    if (blockIdx.x < 8) {
        int m = blockIdx.x;
        if (m < 5) {
            const float *A = nullptr, *B = nullptr;
            if (m == 0) A = W1lc;
            else if (m == 1) A = W1lr;
            else if (m == 2) { A = W1rc; B = W1rw; }
            else if (m == 3) A = W1lw;
            else A = W1rr;
            for (int e = t; e < 2048; e += 256) {
                int k = e >> 5, n = e & 31;
                float v = A[e] + (B ? B[e] : 0.f);
                u16 h = f2bf(v);
                u16 lw = f2bf(v - bf2f(h));
                wt1h[m * 2048 + n * 64 + k] = h;
                wt1l[m * 2048 + n * 64 + k] = lw;
            }
            if (m == 2 && t < HH) b1s[t] = b1c[t] + b1w[t];
        } else {
            int mm = m - 5;
            const float *A = nullptr, *B = nullptr;
            if (mm == 0) A = W2lc;
            else if (mm == 1) { A = W2rc; B = W2rw; }
            else A = W2lw;
            for (int e = t; e < 1024; e += 256) {
                int k = e >> 5, n = e & 31;
                float v = A[e] + (B ? B[e] : 0.f);
                u16 h = f2bf(v);
                u16 lw = f2bf(v - bf2f(h));
                wt2h[mm * 1024 + n * 32 + k] = h;
                wt2l[mm * 1024 + n * 32 + k] = lw;
            }
            if (mm == 1 && t < HH) b2s[t] = b2c[t] + b2w[t];
        }
    } else {
        int pb = blockIdx.x - 8;
        int rel = pb / NB4K, blk = pb - rel * NB4K;
        const int* dst; int shift;
        if (rel == 0)      { dst = cd; shift = 10; }
        else if (rel == 1) { dst = wd; shift = 10; }
        else               { dst = rd; shift = 9;  }
        cnt[t] = 0;
        __syncthreads();
        int e0 = blk * 4096;
        if (e0 + 4096 <= NE) {
            const int4* dv = (const int4*)(dst + e0);
#pragma unroll
            for (int i = 0; i < 4; ++i) {
                int4 v = dv[i * 256 + t];
                atomicAdd(&cnt[v.x >> shift], 1);
                atomicAdd(&cnt[v.y >> shift], 1);
                atomicAdd(&cnt[v.z >> shift], 1);
                atomicAdd(&cnt[v.w >> shift], 1);
            }
        } else {
#pragma unroll
            for (int i = 0; i < 16; ++i) {
                int e = e0 + i * 256 + t;
                if (e < NE) atomicAdd(&cnt[dst[e] >> shift], 1);
            }
        }
        __syncthreads();
        if (t < NCB && cnt[t]) atomicAdd(&gsizes[rel * NCB + t], cnt[t]);
    }
}

// ---------- pass 2: scan bucket sizes -> bases, cursors; one block per relation ----------
__global__ __launch_bounds__(256) void p2_scan_k(
    const int* __restrict__ gsizes, int* __restrict__ bases, int* __restrict__ gcur,
    int* __restrict__ st_c, int* __restrict__ st_w, int* __restrict__ st_r) {
    __shared__ int lds[256];
    int t = threadIdx.x;
    int rel = blockIdx.x;
    int v = (t < NCB) ? gsizes[rel * NCB + t] : 0;
    lds[t] = v; __syncthreads();
#pragma unroll
    for (int o = 1; o < 256; o <<= 1) {
        int x = (t >= o) ? lds[t - o] : 0;
        __syncthreads();
        lds[t] += x;
        __syncthreads();
    }
    int ex = lds[t] - v;   // exclusive
    if (t < NCB) { bases[rel * NCB + t] = ex; gcur[rel * NCB + t] = ex; }
    if (t == 0) {          // sentinels for branchless segment-end loads
        if (rel == 0)      st_c[N_P] = NE;
        else if (rel == 1) st_w[N_P] = NE;
        else               st_r[N_A] = NE;
    }
}

// ---------- pA: p3 bin pass (blocks [0,735)) + t1 blocks [0,TSPLIT) ----------
__global__ __launch_bounds__(256) void pA_k(
    const int* __restrict__ cs, const int* __restrict__ cd,
    const int* __restrict__ ws_, const int* __restrict__ wd,
    const int* __restrict__ rs, const int* __restrict__ rd,
    int* __restrict__ gcur,
    u32* __restrict__ pr_c, u32* __restrict__ pr_w, u32* __restrict__ pr_r,
    const float* __restrict__ xp, const float* __restrict__ xa,
    const u16* __restrict__ wt1h, const u16* __restrict__ wt1l,
    const float* __restrict__ b1s, const float* __restrict__ b1r,
    u16* __restrict__ y_pc, u16* __restrict__ y_pr, u16* __restrict__ y_aw,
    u16* __restrict__ hb_p, u16* __restrict__ hb_a) {
    __shared__ float smem[256 * 34];
    int t = threadIdx.x;
    if (blockIdx.x < NB4K3) {
        // ================= p3: bin edges by coarse bucket =================
        u32* sbuf  = (u32*)smem;             // [4096]
        int* cnt   = (int*)(smem + 4096);    // [256]
        int* sc    = (int*)(smem + 4352);    // [256]
        int* lcur  = (int*)(smem + 4608);    // [256]
        int* gbase = (int*)(smem + 4864);    // [256]
        u8*  bb    = (u8*)(smem + 5120);     // [4096] per-edge bucket id
        int rel = blockIdx.x / NB4K;
        int blk = blockIdx.x - rel * NB4K;
        const int *src, *dst; int shift; u32* out;
        if (rel == 0)      { src = cs;  dst = cd; shift = 10; out = pr_c; }
        else if (rel == 1) { src = ws_; dst = wd; shift = 10; out = pr_w; }
        else               { src = rs;  dst = rd; shift = 9;  out = pr_r; }
        cnt[t] = 0;
        __syncthreads();
        int e0 = blk * 4096;
        int myd[16], mys[16];
        if (e0 + 4096 <= NE) {
            const int4* dv = (const int4*)(dst + e0);
            const int4* sv = (const int4*)(src + e0);
#pragma unroll
            for (int i = 0; i < 4; ++i) {
                int4 v = dv[i * 256 + t];
                int4 s = sv[i * 256 + t];
                myd[4 * i] = v.x; myd[4 * i + 1] = v.y; myd[4 * i + 2] = v.z; myd[4 * i + 3] = v.w;
                mys[4 * i] = s.x; mys[4 * i + 1] = s.y; mys[4 * i + 2] = s.z; mys[4 * i + 3] = s.w;
                atomicAdd(&cnt[v.x >> shift], 1);
                atomicAdd(&cnt[v.y >> shift], 1);
                atomicAdd(&cnt[v.z >> shift], 1);
                atomicAdd(&cnt[v.w >> shift], 1);
            }
        } else {
#pragma unroll
            for (int i = 0; i < 4; ++i) {
#pragma unroll
                for (int c = 0; c < 4; ++c) {
                    int e = e0 + (i * 256 + t) * 4 + c;
                    int idx = 4 * i + c;
                    if (e < NE) {
                        myd[idx] = dst[e]; mys[idx] = src[e];
                        atomicAdd(&cnt[myd[idx] >> shift], 1);
                    } else { myd[idx] = -1; mys[idx] = 0; }
                }
            }
        }
        __syncthreads();
        int v = cnt[t];
        sc[t] = v; __syncthreads();
#pragma unroll
        for (int o = 1; o < 256; o <<= 1) {
            int x = (t >= o) ? sc[t - o] : 0;
            __syncthreads();
            sc[t] += x;
            __syncthreads();
        }
        int ex = sc[t] - v;
        __syncthreads();
        sc[t] = ex;
        lcur[t] = ex;
        if (t < NCB) gbase[t] = atomicAdd(&gcur[rel * NCB + t], cnt[t]);
        __syncthreads();
#pragma unroll
        for (int i = 0; i < 16; ++i) {
            if (myd[i] >= 0) {
                int d = myd[i];
                int cb = d >> shift;
                u32 dloc = (u32)(d - (cb << shift));
                u32 pk = (dloc << 18) | (u32)mys[i];
                int p = atomicAdd(&lcur[cb], 1);
                sbuf[p] = pk;
                bb[p] = (u8)cb;
            }
        }
        __syncthreads();
        int nvalid = min(4096, NE - e0);
        for (int i = t; i < nvalid; i += 256) {
            int cb = bb[i];
            out[gbase[cb] + (i - sc[cb])] = sbuf[i];
        }
    } else {
        t1_body(blockIdx.x - NB4K3, smem, xp, xa, wt1h, wt1l, b1s, b1r,
                y_pc, y_pr, y_aw, hb_p, hb_a);
    }
}

// ---------- pB: p4 counting sort (blocks [0,588)) + t1 blocks [TSPLIT,1173) ----------
__global__ __launch_bounds__(256) void pB_k(
    const int* __restrict__ bases, const int* __restrict__ gsizes,
    const u32* __restrict__ pr_c, const u32* __restrict__ pr_w, const u32* __restrict__ pr_r,
    int* __restrict__ bkt_c, int* __restrict__ bkt_w, int* __restrict__ bkt_r,
    int* __restrict__ st_c, int* __restrict__ st_w, int* __restrict__ st_r,
    const float* __restrict__ xp, const float* __restrict__ xa,
    const u16* __restrict__ wt1h, const u16* __restrict__ wt1l,
    const float* __restrict__ b1s, const float* __restrict__ b1r,
    u16* __restrict__ y_pc, u16* __restrict__ y_pr, u16* __restrict__ y_aw,
    u16* __restrict__ hb_p, u16* __restrict__ hb_a) {
    __shared__ float smem[10496];   // 41984 B: p4 {sin 8192u32, cnt 1024, sc2 1024, tmp 256}
    int t = threadIdx.x;
    if (blockIdx.x < 3 * NCB) {
        u32* sin = (u32*)smem;                 // [8192]
        int* cnt = (int*)(sin + P4CAP);        // [1024]
        int* sc2 = cnt + 1024;                 // [1024]
        int* tmp = sc2 + 1024;                 // [256]
        int rel = blockIdx.x / NCB;
        int b = blockIdx.x - rel * NCB;
        const u32* pr; int* bkt; int* st; int width, n;
        if (rel == 0)      { pr = pr_c; bkt = bkt_c; st = st_c; width = 1024; n = N_P; }
        else if (rel == 1) { pr = pr_w; bkt = bkt_w; st = st_w; width = 1024; n = N_P; }
        else               { pr = pr_r; bkt = bkt_r; st = st_r; width = 512;  n = N_A; }
        int base = bases[rel * NCB + b];
        int size = min(gsizes[rel * NCB + b], P4CAP);
        int d0 = b * width;
        int nd = min(width, n - d0);
        if (nd <= 0) return;
#pragma unroll
        for (int j = t; j < 1024; j += 256) cnt[j] = 0;
        __syncthreads();
        for (int i = t; i < size; i += 256) {
            u32 pk = pr[base + i];
            sin[i] = pk;
            atomicAdd(&cnt[pk >> 18], 1);
        }
        __syncthreads();
        int j0 = 4 * t;
        int c0 = cnt[j0], c1 = cnt[j0 + 1], c2 = cnt[j0 + 2], c3 = cnt[j0 + 3];
        int tot = c0 + c1 + c2 + c3;
        tmp[t] = tot; __syncthreads();
#pragma unroll
        for (int o = 1; o < 256; o <<= 1) {
            int x = (t >= o) ? tmp[t - o] : 0;
            __syncthreads();
            tmp[t] += x;
            __syncthreads();
        }
        int pre = tmp[t] - tot;
        sc2[j0] = pre;
        sc2[j0 + 1] = pre + c0;
        sc2[j0 + 2] = pre + c0 + c1;
        sc2[j0 + 3] = pre + c0 + c1 + c2;
        __syncthreads();
        for (int j = t; j < nd; j += 256) st[d0 + j] = base + sc2[j];
#pragma unroll
        for (int j = t; j < 1024; j += 256) cnt[j] = 0;
        __syncthreads();
        for (int i = t; i < size; i += 256) {
            u32 pk = sin[i];
            int dl = (int)(pk >> 18);
            int pos = sc2[dl] + atomicAdd(&cnt[dl], 1);
            bkt[base + pos] = (int)((pk & 0x3FFFFu) * HH);  // pre-scaled (u16 units)
        }
    } else {
        t1_body(blockIdx.x - 3 * NCB + TSPLIT, smem, xp, xa, wt1h, wt1l, b1s, b1r,
                y_pc, y_pr, y_aw, hb_p, hb_a);
    }
}

// ---------- L1 gather-aggregate (dual-stream), writes RELU'd hb ----------
__global__ __launch_bounds__(256) void agg1_k(
    const u16* __restrict__ y_pc, const u16* __restrict__ y_aw,
    const u16* __restrict__ y_pr,
    const int* __restrict__ st_c, const int* __restrict__ bkt_c,
    const int* __restrict__ st_w, const int* __restrict__ bkt_w,
    const int* __restrict__ st_r, const int* __restrict__ bkt_r,
    u32* __restrict__ hb_p, u32* __restrict__ hb_a) {
    int t = threadIdx.x, g = t >> 4, lane = t & 15;
    if (blockIdx.x < NB_P16) {
        int row = blockIdx.x * 16 + g;
        u32 self = hb_p[(size_t)row * (HH / 2) + lane];   // prefetch before gathers
        int s0 = st_c[row], e0 = st_c[row + 1];           // sentinel-terminated
        int s1 = st_w[row], e1 = st_w[row + 1];
        float cx, cy, wx, wy;
        gseg_dual(y_pc, bkt_c, s0, e0, y_aw, bkt_w, s1, e1, lane, cx, cy, wx, wy);
        int d0 = e0 - s0, d1 = e1 - s1;
        float iv0 = 1.0f / (float)(d0 < 1 ? 1 : d0);
        float iv1 = 1.0f / (float)(d1 < 1 ? 1 : d1);
        float ax = fmaxf(cx * iv0 + wx * iv1 + lo_f(self), 0.f);   // relu here
        float ay = fmaxf(cy * iv0 + wy * iv1 + hi_f(self), 0.f);
        hb_p[(size_t)row * (HH / 2) + lane] = cvtpk(ax, ay);
    } else {
        int row = (blockIdx.x - NB_P16) * 16 + g;
        u32 self = hb_a[(size_t)row * (HH / 2) + lane];
        int s = st_r[row], e = st_r[row + 1];
        int mid = (s + e) >> 1;
        float ax0, ay0, ax1, ay1;
        gseg_dual(y_pr, bkt_r, s, mid, y_pr, bkt_r, mid, e, lane, ax0, ay0, ax1, ay1);
        int dg = e - s;
        float iv = 1.0f / (float)(dg < 1 ? 1 : dg);
        float ax = fmaxf((ax0 + ax1) * iv + lo_f(self), 0.f);      // relu here
        float ay = fmaxf((ay0 + ay1) * iv + hi_f(self), 0.f);
        hb_a[(size_t)row * (HH / 2) + lane] = cvtpk(ax, ay);
    }
}

// ---------- L2: gather relu'd hb means + full MFMA epilogue (t2 folded in) ----------
__global__ __launch_bounds__(256) void agg2_k(
    const u16* __restrict__ hb_p, const u16* __restrict__ hb_a,
    const int* __restrict__ st_c, const int* __restrict__ bkt_c,
    const int* __restrict__ st_w, const int* __restrict__ bkt_w,
    const u16* __restrict__ wt2h, const u16* __restrict__ wt2l,
    const float* __restrict__ b2s, float* __restrict__ out) {
    __shared__ float mcs[16][34];
    __shared__ float mws[16][34];
    __shared__ float cso[16][34];
    int t = threadIdx.x, g = t >> 4, lane = t & 15;
    int row0 = blockIdx.x * 16;
    int row = row0 + g;
    int s0 = st_c[row], e0 = st_c[row + 1];
    int s1 = st_w[row], e1 = st_w[row + 1];
    float cx, cy, wx, wy;
    gseg_dual(hb_p, bkt_c, s0, e0, hb_a, bkt_w, s1, e1, lane, cx, cy, wx, wy);
    int d0 = e0 - s0, d1 = e1 - s1;
    float iv0 = 1.0f / (float)(d0 < 1 ? 1 : d0);
    float iv1 = 1.0f / (float)(d1 < 1 ? 1 : d1);
    mcs[g][2 * lane] = cx * iv0;  mcs[g][2 * lane + 1] = cy * iv0;
    mws[g][2 * lane] = wx * iv1;  mws[g][2 * lane + 1] = wy * iv1;
    __syncthreads();
    if (t < 64) {
        int lm = t & 15, lk = t >> 4;
        bf16x8 as_ = *(const bf16x8*)(hb_p + (size_t)(row0 + lm) * HH + lk * 8);
        bf16x8 mch, mcl, mwh, mwl;
        {
            union { u32 u[4]; bf16x8 v; } H, L;
#pragma unroll
            for (int j = 0; j < 4; ++j) {
                float f0 = mcs[lm][lk * 8 + 2 * j];
                float f1 = mcs[lm][lk * 8 + 2 * j + 1];
                u32 u0 = __float_as_uint(f0), u1 = __float_as_uint(f1);
                u32 m0 = u0 & 0xffff0000u, m1 = u1 & 0xffff0000u;
                H.u[j] = (u0 >> 16) | m1;
                L.u[j] = cvtpk(f0 - __uint_as_float(m0), f1 - __uint_as_float(m1));
            }
            mch = H.v; mcl = L.v;
#pragma unroll
            for (int j = 0; j < 4; ++j) {
                float f0 = mws[lm][lk * 8 + 2 * j];
                float f1 = mws[lm][lk * 8 + 2 * j + 1];
                u32 u0 = __float_as_uint(f0), u1 = __float_as_uint(f1);
                u32 m0 = u0 & 0xffff0000u, m1 = u1 & 0xffff0000u;
                H.u[j] = (u0 >> 16) | m1;
                L.u[j] = cvtpk(f0 - __uint_as_float(m0), f1 - __uint_as_float(m1));
            }
            mwh = H.v; mwl = L.v;
        }
#pragma unroll
        for (int ct = 0; ct < 2; ++ct) {
            int boff = (ct * 16 + lm) * 32 + lk * 8;
            bf16x8 Bch = *(const bf16x8*)(wt2h + boff);
            bf16x8 Bcl = *(const bf16x8*)(wt2l + boff);
            bf16x8 Bsh = *(const bf16x8*)(wt2h + 1024 + boff);
            bf16x8 Bsl = *(const bf16x8*)(wt2l + 1024 + boff);
            bf16x8 Bwh = *(const bf16x8*)(wt2h + 2048 + boff);
            bf16x8 Bwl = *(const bf16x8*)(wt2l + 2048 + boff);
            float bb = b2s[ct * 16 + lm];
            f32x4 acc = {bb, bb, bb, bb};
            acc = __builtin_amdgcn_mfma_f32_16x16x32_bf16(as_, Bsh, acc, 0, 0, 0);
            acc = __builtin_amdgcn_mfma_f32_16x16x32_bf16(as_, Bsl, acc, 0, 0, 0);
            acc = __builtin_amdgcn_mfma_f32_16x16x32_bf16(mch, Bch, acc, 0, 0, 0);
            acc = __builtin_amdgcn_mfma_f32_16x16x32_bf16(mcl, Bch, acc, 0, 0, 0);
            acc = __builtin_amdgcn_mfma_f32_16x16x32_bf16(mch, Bcl, acc, 0, 0, 0);
            acc = __builtin_amdgcn_mfma_f32_16x16x32_bf16(mwh, Bwh, acc, 0, 0, 0);
            acc = __builtin_amdgcn_mfma_f32_16x16x32_bf16(mwl, Bwh, acc, 0, 0, 0);
            acc = __builtin_amdgcn_mfma_f32_16x16x32_bf16(mwh, Bwl, acc, 0, 0, 0);
#pragma unroll
            for (int r = 0; r < 4; ++r)
                cso[lk * 4 + r][ct * 16 + lm] = acc[r];
        }
    }
    __syncthreads();
    int r = t >> 4, c = (t & 15) * 2;
    *(float2*)(out + (size_t)(row0 + r) * HH + c) = make_float2(cso[r][c], cso[r][c + 1]);
}

extern "C" void kernel_launch(void* const* d_in, const int* in_sizes, int n_in,
                              void* d_out, int out_size, void* d_ws, size_t ws_size,
                              hipStream_t stream) {
    const float* x_p  = (const float*)d_in[0];
    const float* x_a  = (const float*)d_in[1];
    const int* c_src  = (const int*)d_in[2];
    const int* c_dst  = (const int*)d_in[3];
    const int* w_src  = (const int*)d_in[4];
    const int* w_dst  = (const int*)d_in[5];
    const int* r_src  = (const int*)d_in[6];
    const int* r_dst  = (const int*)d_in[7];
    const float* W1l_c = (const float*)d_in[8];
    const float* W1r_c = (const float*)d_in[9];
    const float* b1_c  = (const float*)d_in[10];
    const float* W1l_w = (const float*)d_in[11];
    const float* W1r_w = (const float*)d_in[12];
    const float* b1_w  = (const float*)d_in[13];
    const float* W1l_r = (const float*)d_in[14];
    const float* W1r_r = (const float*)d_in[15];
    const float* b1_r  = (const float*)d_in[16];
    const float* W2l_c = (const float*)d_in[17];
    const float* W2r_c = (const float*)d_in[18];
    const float* b2_c  = (const float*)d_in[19];
    const float* W2l_w = (const float*)d_in[20];
    const float* W2r_w = (const float*)d_in[21];
    const float* b2_w  = (const float*)d_in[22];

    // ---- workspace layout (st arrays +1 sentinel each) ----
    int* gsizes = (int*)d_ws;
    int* bases  = gsizes + 3 * NCB;
    int* gcur   = bases + 3 * NCB;
    int* st_c   = gcur + 3 * NCB;
    int* st_w   = st_c + N_P + 1;
    int* st_r   = st_w + N_P + 1;
    int* bkt_c  = st_r + N_A + 1;
    int* bkt_w  = bkt_c + NE;
    int* bkt_r  = bkt_w + NE;
    u16* wt1h  = (u16*)(bkt_r + NE);      // 5*2048
    u16* wt1l  = wt1h + 5 * 2048;
    u16* wt2h  = wt1l + 5 * 2048;         // 3*1024
    u16* wt2l  = wt2h + 3 * 1024;
    float* b1s = (float*)(wt2l + 3 * 1024);
    float* b2s = b1s + HH;
    u16* hb_p  = (u16*)(b2s + HH);
    u16* hb_a  = hb_p + (size_t)N_P * HH;
    u16* y_pc  = hb_a + (size_t)N_A * HH;
    u16* y_pr  = y_pc + (size_t)N_P * HH;
    u16* y_aw  = y_pr + (size_t)N_P * HH;
    float* tail = (float*)(y_aw + (size_t)N_A * HH);   // pr staging region
    u32* pr_c  = (u32*)tail;
    u32* pr_w  = pr_c + NE;
    u32* pr_r  = pr_w + NE;
    float* outp = (float*)d_out;

    const size_t need = ((uintptr_t)(pr_r + NE)) - (uintptr_t)d_ws;
    if (ws_size < need) return;  // fail loudly, not OOB

    hipMemsetAsync(gsizes, 0, 3 * NCB * sizeof(int), stream);
    prep1_k<<<8 + NB4K3, 256, 0, stream>>>(W1l_c, W1l_r, W1r_c, W1r_w, W1l_w, W1r_r,
                                           W2l_c, W2r_c, W2r_w, W2l_w,
                                           b1_c, b1_w, b2_c, b2_w,
                                           wt1h, wt1l, wt2h, wt2l, b1s, b2s,
                                           c_dst, w_dst, r_dst, gsizes);
    p2_scan_k<<<3, 256, 0, stream>>>(gsizes, bases, gcur, st_c, st_w, st_r);
    pA_k<<<NB4K3 + TSPLIT, 256, 0, stream>>>(
        c_src, c_dst, w_src, w_dst, r_src, r_dst, gcur, pr_c, pr_w, pr_r,
        x_p, x_a, wt1h, wt1l, b1s, b1_r, y_pc, y_pr, y_aw, hb_p, hb_a);
    pB_k<<<3 * NCB + (NB_T1 - TSPLIT), 256, 0, stream>>>(
        bases, gsizes, pr_c, pr_w, pr_r, bkt_c, bkt_w, bkt_r, st_c, st_w, st_r,
        x_p, x_a, wt1h, wt1l, b1s, b1_r, y_pc, y_pr, y_aw, hb_p, hb_a);
    agg1_k<<<NB_P16 + NB_A16, 256, 0, stream>>>(y_pc, y_aw, y_pr,
                                                st_c, bkt_c, st_w, bkt_w, st_r, bkt_r,
                                                (u32*)hb_p, (u32*)hb_a);
    agg2_k<<<NB_P16, 256, 0, stream>>>(hb_p, hb_a, st_c, bkt_c, st_w, bkt_w,
                                       wt2h, wt2l, b2s, outp);
}

// Round 11
// 363.321 us; speedup vs baseline: 1.0751x; 1.0751x over previous
//
#include <hip/hip_runtime.h>

typedef unsigned short u16;
typedef unsigned int   u32;
typedef unsigned char  u8;
typedef __attribute__((ext_vector_type(8))) short bf16x8;
typedef __attribute__((ext_vector_type(4))) float f32x4;

#define N_P 200000
#define N_A 100000
#define DD  64
#define HH  32
#define NE  1000000
#define NBP 782          // (N_P+255)/256
#define NBA 391          // (N_A+255)/256
#define NB4K 245         // ceil(NE/4096)
#define NCB 196          // coarse buckets per relation (paper: 1024-wide, author: 512-wide)
#define P4CAP 8192       // max edges per coarse bucket (mean 5102, sigma ~71)
#define NB_P16 12500     // N_P/16 (exact)
#define NB_A16 6250      // N_A/16 (exact)
#define NB4K3 735        // 3*NB4K (p3 part of fused kernel)

// ---------- bf16 helpers ----------
__device__ inline float bf2f(u16 u) { return __uint_as_float(((u32)u) << 16); }
__device__ inline u16 f2bf(float f) {
    u32 u = __float_as_uint(f);
    u += 0x7fffu + ((u >> 16) & 1u);
    return (u16)(u >> 16);
}
__device__ inline float lo_f(u32 m) { return __uint_as_float(m << 16); }
__device__ inline float hi_f(u32 m) { return __uint_as_float(m & 0xffff0000u); }
// HW packed f32->2xbf16 (RNE), 1 instr
__device__ inline u32 cvtpk(float a, float b) {
    u32 r;
    asm("v_cvt_pk_bf16_f32 %0, %1, %2" : "=v"(r) : "v"(a), "v"(b));
    return r;
}

// ---------- dual-stream gather-sum (R8 form: low-VGPR, at random-line roofline) ----------
__device__ inline void gseg_dual(
    const u16* __restrict__ yA, const int* __restrict__ bkA, int s0, int e0,
    const u16* __restrict__ yB, const int* __restrict__ bkB, int s1, int e1,
    int lane, float& axo, float& ayo, float& bxo, float& byo) {
    float ax = 0.f, ay = 0.f, bx = 0.f, by = 0.f;
    int lastA = min(max(e0 - 1, s0), NE - 1);
    int lastB = min(max(e1 - 1, s1), NE - 1);
    for (int j0 = s0, j1 = s1; (j0 < e0) || (j1 < e1); j0 += 8, j1 += 8) {
        int ia[8], ib[8];
#pragma unroll
        for (int i = 0; i < 8; ++i) ia[i] = bkA[min(j0 + i, lastA)];
#pragma unroll
        for (int i = 0; i < 8; ++i) ib[i] = bkB[min(j1 + i, lastB)];
        u32 ma[8], mb[8];
#pragma unroll
        for (int i = 0; i < 8; ++i)
            ma[i] = *(const u32*)(yA + (size_t)(u32)ia[i] + lane * 2);
#pragma unroll
        for (int i = 0; i < 8; ++i)
            mb[i] = *(const u32*)(yB + (size_t)(u32)ib[i] + lane * 2);
#pragma unroll
        for (int i = 0; i < 8; ++i) {
            u32 va = (j0 + i < e0) ? ma[i] : 0u;
            ax += lo_f(va); ay += hi_f(va);
        }
#pragma unroll
        for (int i = 0; i < 8; ++i) {
            u32 vb = (j1 + i < e1) ? mb[i] : 0u;
            bx += lo_f(vb); by += hi_f(vb);
        }
    }
    axo = ax; ayo = ay; bxo = bx; byo = by;
}

// ---------- pass 1: coarse-bucket histogram (int4 loads) ----------
__global__ __launch_bounds__(256) void p1_hist_k(
    const int* __restrict__ cd, const int* __restrict__ wd, const int* __restrict__ rd,
    int* __restrict__ gsizes) {
    int rel = blockIdx.y;
    const int* dst; int shift;
    if (rel == 0)      { dst = cd; shift = 10; }
    else if (rel == 1) { dst = wd; shift = 10; }
    else               { dst = rd; shift = 9;  }
    __shared__ int cnt[256];
    int t = threadIdx.x;
    cnt[t] = 0;
    __syncthreads();
    int e0 = blockIdx.x * 4096;
    if (e0 + 4096 <= NE) {
        const int4* dv = (const int4*)(dst + e0);
#pragma unroll
        for (int i = 0; i < 4; ++i) {
            int4 v = dv[i * 256 + t];
            atomicAdd(&cnt[v.x >> shift], 1);
            atomicAdd(&cnt[v.y >> shift], 1);
            atomicAdd(&cnt[v.z >> shift], 1);
            atomicAdd(&cnt[v.w >> shift], 1);
        }
    } else {
#pragma unroll
        for (int i = 0; i < 16; ++i) {
            int e = e0 + i * 256 + t;
            if (e < NE) atomicAdd(&cnt[dst[e] >> shift], 1);
        }
    }
    __syncthreads();
    if (t < NCB && cnt[t]) atomicAdd(&gsizes[rel * NCB + t], cnt[t]);
}

// ---------- pass 2: scan bucket sizes -> bases, cursors; one block per relation ----------
__global__ __launch_bounds__(256) void p2_scan_k(
    const int* __restrict__ gsizes, int* __restrict__ bases, int* __restrict__ gcur,
    int* __restrict__ st_c, int* __restrict__ st_w, int* __restrict__ st_r) {
    __shared__ int lds[256];
    int t = threadIdx.x;
    int rel = blockIdx.x;
    int v = (t < NCB) ? gsizes[rel * NCB + t] : 0;
    lds[t] = v; __syncthreads();
#pragma unroll
    for (int o = 1; o < 256; o <<= 1) {
        int x = (t >= o) ? lds[t - o] : 0;
        __syncthreads();
        lds[t] += x;
        __syncthreads();
    }
    int ex = lds[t] - v;   // exclusive
    if (t < NCB) { bases[rel * NCB + t] = ex; gcur[rel * NCB + t] = ex; }
    if (t == 0) {          // sentinels for branchless segment-end loads
        if (rel == 0)      st_c[N_P] = NE;
        else if (rel == 1) st_w[N_P] = NE;
        else               st_r[N_A] = NE;
    }
}

// ---------- FUSED: p3 bin pass (blocks [0,735)) + t1 MFMA transforms (rest) ----------
__global__ __launch_bounds__(256) void p3t1_k(
    // p3 args
    const int* __restrict__ cs, const int* __restrict__ cd,
    const int* __restrict__ ws_, const int* __restrict__ wd,
    const int* __restrict__ rs, const int* __restrict__ rd,
    int* __restrict__ gcur,
    u32* __restrict__ pr_c, u32* __restrict__ pr_w, u32* __restrict__ pr_r,
    // t1 args
    const float* __restrict__ xp, const float* __restrict__ xa,
    const u16* __restrict__ wt1h, const u16* __restrict__ wt1l,
    const float* __restrict__ b1s, const float* __restrict__ b1r,
    u16* __restrict__ y_pc, u16* __restrict__ y_pr, u16* __restrict__ y_aw,
    u16* __restrict__ hb_p, u16* __restrict__ hb_a) {
    __shared__ float smem[256 * 34];     // t1: Cs staging; p3: carved below
    int t = threadIdx.x;
    if (blockIdx.x < NB4K3) {
        // ================= p3: bin edges by coarse bucket =================
        u32* sbuf  = (u32*)smem;             // [4096]
        int* cnt   = (int*)(smem + 4096);    // [256]
        int* sc    = (int*)(smem + 4352);    // [256]
        int* lcur  = (int*)(smem + 4608);    // [256]
        int* gbase = (int*)(smem + 4864);    // [256]
        u8*  bb    = (u8*)(smem + 5120);     // [4096] per-edge bucket id
        int rel = blockIdx.x / NB4K;
        int blk = blockIdx.x - rel * NB4K;
        const int *src, *dst; int shift; u32* out;
        if (rel == 0)      { src = cs;  dst = cd; shift = 10; out = pr_c; }
        else if (rel == 1) { src = ws_; dst = wd; shift = 10; out = pr_w; }
        else               { src = rs;  dst = rd; shift = 9;  out = pr_r; }
        cnt[t] = 0;
        __syncthreads();
        int e0 = blk * 4096;
        int myd[16], mys[16];
        if (e0 + 4096 <= NE) {
            const int4* dv = (const int4*)(dst + e0);
            const int4* sv = (const int4*)(src + e0);
#pragma unroll
            for (int i = 0; i < 4; ++i) {
                int4 v = dv[i * 256 + t];
                int4 s = sv[i * 256 + t];
                myd[4 * i] = v.x; myd[4 * i + 1] = v.y; myd[4 * i + 2] = v.z; myd[4 * i + 3] = v.w;
                mys[4 * i] = s.x; mys[4 * i + 1] = s.y; mys[4 * i + 2] = s.z; mys[4 * i + 3] = s.w;
                atomicAdd(&cnt[v.x >> shift], 1);
                atomicAdd(&cnt[v.y >> shift], 1);
                atomicAdd(&cnt[v.z >> shift], 1);
                atomicAdd(&cnt[v.w >> shift], 1);
            }
        } else {
#pragma unroll
            for (int i = 0; i < 4; ++i) {
#pragma unroll
                for (int c = 0; c < 4; ++c) {
                    int e = e0 + (i * 256 + t) * 4 + c;
                    int idx = 4 * i + c;
                    if (e < NE) {
                        myd[idx] = dst[e]; mys[idx] = src[e];
                        atomicAdd(&cnt[myd[idx] >> shift], 1);
                    } else { myd[idx] = -1; mys[idx] = 0; }
                }
            }
        }
        __syncthreads();
        int v = cnt[t];
        sc[t] = v; __syncthreads();
#pragma unroll
        for (int o = 1; o < 256; o <<= 1) {
            int x = (t >= o) ? sc[t - o] : 0;
            __syncthreads();
            sc[t] += x;
            __syncthreads();
        }
        int ex = sc[t] - v;
        __syncthreads();
        sc[t] = ex;
        lcur[t] = ex;
        if (t < NCB) gbase[t] = atomicAdd(&gcur[rel * NCB + t], cnt[t]);
        __syncthreads();
#pragma unroll
        for (int i = 0; i < 16; ++i) {
            if (myd[i] >= 0) {
                int d = myd[i];
                int cb = d >> shift;
                u32 dloc = (u32)(d - (cb << shift));
                u32 pk = (dloc << 18) | (u32)mys[i];
                int p = atomicAdd(&lcur[cb], 1);
                sbuf[p] = pk;
                bb[p] = (u8)cb;
            }
        }
        __syncthreads();
        int nvalid = min(4096, NE - e0);
        for (int i = t; i < nvalid; i += 256) {
            int cb = bb[i];
            out[gbase[cb] + (i - sc[cb])] = sbuf[i];
        }
    } else {
        // ================= t1: MFMA transforms, barrier-free =================
        float* Cs = smem;
        int w = t >> 6, l = t & 63;
        int lm = l & 15, lk = l >> 4;
        int bx = blockIdx.x - NB4K3;
        bool paper = bx < NBP;
        int row0 = (paper ? bx : bx - NBP) * 256;
        const float* x = paper ? xp : xa;
        int NROW = paper ? N_P : N_A;
        int nv = min(256, NROW - row0);
        bf16x8 xh[4][2], xl[4][2];
#pragma unroll
        for (int i = 0; i < 4; ++i) {
            int rowg = min(row0 + w * 64 + i * 16 + lm, NROW - 1);
            const float* rp = x + (size_t)rowg * DD + lk * 8;
#pragma unroll
            for (int kc = 0; kc < 2; ++kc) {
                float4 a = *(const float4*)(rp + kc * 32);
                float4 b = *(const float4*)(rp + kc * 32 + 4);
                float f[8] = {a.x, a.y, a.z, a.w, b.x, b.y, b.z, b.w};
                union { u32 u[4]; bf16x8 v; } H, L;
#pragma unroll
                for (int j = 0; j < 4; ++j) {
                    u32 u0 = __float_as_uint(f[2 * j]);
                    u32 u1 = __float_as_uint(f[2 * j + 1]);
                    u32 m0 = u0 & 0xffff0000u;
                    u32 m1 = u1 & 0xffff0000u;
                    H.u[j] = (u0 >> 16) | m1;
                    float l0 = f[2 * j]     - __uint_as_float(m0);
                    float l1 = f[2 * j + 1] - __uint_as_float(m1);
                    L.u[j] = cvtpk(l0, l1);
                }
                xh[i][kc] = H.v; xl[i][kc] = L.v;
            }
        }
        int nw = paper ? 3 : 2;
#pragma unroll 1
        for (int iw = 0; iw < nw; ++iw) {
            int mat = paper ? iw : (3 + iw);
            const u16* Wh = wt1h + mat * 2048;
            const u16* Wl = wt1l + mat * 2048;
            bf16x8 Bh[2][2], Bl[2][2];
#pragma unroll
            for (int ct = 0; ct < 2; ++ct)
#pragma unroll
                for (int kc = 0; kc < 2; ++kc) {
                    int off = (ct * 16 + lm) * 64 + kc * 32 + lk * 8;
                    Bh[ct][kc] = *(const bf16x8*)(Wh + off);
                    Bl[ct][kc] = *(const bf16x8*)(Wl + off);
                }
            float bv[2] = {0.f, 0.f};
            if (paper && iw == 2)  { bv[0] = b1s[lm]; bv[1] = b1s[16 + lm]; }
            if (!paper && iw == 1) { bv[0] = b1r[lm]; bv[1] = b1r[16 + lm]; }
#pragma unroll
            for (int i = 0; i < 4; ++i) {
#pragma unroll
                for (int ct = 0; ct < 2; ++ct) {
                    f32x4 acc = {bv[ct], bv[ct], bv[ct], bv[ct]};
                    acc = __builtin_amdgcn_mfma_f32_16x16x32_bf16(xh[i][0], Bh[ct][0], acc, 0, 0, 0);
                    acc = __builtin_amdgcn_mfma_f32_16x16x32_bf16(xh[i][1], Bh[ct][1], acc, 0, 0, 0);
                    acc = __builtin_amdgcn_mfma_f32_16x16x32_bf16(xl[i][0], Bh[ct][0], acc, 0, 0, 0);
                    acc = __builtin_amdgcn_mfma_f32_16x16x32_bf16(xl[i][1], Bh[ct][1], acc, 0, 0, 0);
                    acc = __builtin_amdgcn_mfma_f32_16x16x32_bf16(xh[i][0], Bl[ct][0], acc, 0, 0, 0);
                    acc = __builtin_amdgcn_mfma_f32_16x16x32_bf16(xh[i][1], Bl[ct][1], acc, 0, 0, 0);
                    int rbase = w * 64 + i * 16 + lk * 4;
#pragma unroll
                    for (int r = 0; r < 4; ++r)
                        Cs[(rbase + r) * 34 + ct * 16 + lm] = acc[r];
                }
            }
            asm volatile("s_waitcnt lgkmcnt(0)" ::: "memory");
            u16* outp;
            if (paper) outp = (iw == 0) ? y_pc : (iw == 1) ? y_pr : hb_p;
            else       outp = (iw == 0) ? y_aw : hb_a;
            u32* g = (u32*)(outp + (size_t)row0 * HH);
#pragma unroll
            for (int p = 0; p < 4; ++p) {
                int j = p * 64 + l;
                int rl = w * 64 + (j >> 2);
                if (rl < nv) {
                    const float* q = Cs + rl * 34 + (j & 3) * 8;
                    u32 o[4];
#pragma unroll
                    for (int jj = 0; jj < 4; ++jj)
                        o[jj] = cvtpk(q[2 * jj], q[2 * jj + 1]);
                    *(uint4*)(g + ((size_t)w * 256 + j) * 4) = make_uint4(o[0], o[1], o[2], o[3]);
                }
            }
            asm volatile("" ::: "memory");
        }
    }
}

// ---------- pass 4: per-bucket LDS counting sort (R8 256-thread form) ----------
__global__ __launch_bounds__(256) void p4_sort_k(
    const int* __restrict__ bases, const int* __restrict__ gsizes,
    const u32* __restrict__ pr_c, const u32* __restrict__ pr_w, const u32* __restrict__ pr_r,
    int* __restrict__ bkt_c, int* __restrict__ bkt_w, int* __restrict__ bkt_r,
    int* __restrict__ st_c, int* __restrict__ st_w, int* __restrict__ st_r) {
    int rel = blockIdx.y;
    const u32* pr; int* bkt; int* st; int width, n;
    if (rel == 0)      { pr = pr_c; bkt = bkt_c; st = st_c; width = 1024; n = N_P; }
    else if (rel == 1) { pr = pr_w; bkt = bkt_w; st = st_w; width = 1024; n = N_P; }
    else               { pr = pr_r; bkt = bkt_r; st = st_r; width = 512;  n = N_A; }
    __shared__ u32 sin[P4CAP];
    __shared__ int cnt[1024], sc2[1024], tmp[256];
    int t = threadIdx.x;
    int b = blockIdx.x;
    int base = bases[rel * NCB + b];
    int size = min(gsizes[rel * NCB + b], P4CAP);
    int d0 = b * width;
    int nd = min(width, n - d0);
    if (nd <= 0) return;
#pragma unroll
    for (int j = t; j < 1024; j += 256) cnt[j] = 0;
    __syncthreads();
    for (int i = t; i < size; i += 256) {
        u32 pk = pr[base + i];
        sin[i] = pk;
        atomicAdd(&cnt[pk >> 18], 1);
    }
    __syncthreads();
    int j0 = 4 * t;
    int c0 = cnt[j0], c1 = cnt[j0 + 1], c2 = cnt[j0 + 2], c3 = cnt[j0 + 3];
    int tot = c0 + c1 + c2 + c3;
    tmp[t] = tot; __syncthreads();
#pragma unroll
    for (int o = 1; o < 256; o <<= 1) {
        int x = (t >= o) ? tmp[t - o] : 0;
        __syncthreads();
        tmp[t] += x;
        __syncthreads();
    }
    int pre = tmp[t] - tot;
    sc2[j0] = pre;
    sc2[j0 + 1] = pre + c0;
    sc2[j0 + 2] = pre + c0 + c1;
    sc2[j0 + 3] = pre + c0 + c1 + c2;
    __syncthreads();
    for (int j = t; j < nd; j += 256) st[d0 + j] = base + sc2[j];
#pragma unroll
    for (int j = t; j < 1024; j += 256) cnt[j] = 0;
    __syncthreads();
    for (int i = t; i < size; i += 256) {
        u32 pk = sin[i];
        int dl = (int)(pk >> 18);
        int pos = sc2[dl] + atomicAdd(&cnt[dl], 1);
        bkt[base + pos] = (int)((pk & 0x3FFFFu) * HH);  // pre-scaled (u16 units)
    }
}

// ---------- weight prep: transpose + hi/lo bf16 split (+ gsizes zeroing) ----------
__global__ __launch_bounds__(256) void prep_w_k(
    const float* __restrict__ W1lc, const float* __restrict__ W1lr,
    const float* __restrict__ W1rc, const float* __restrict__ W1rw,
    const float* __restrict__ W1lw, const float* __restrict__ W1rr,
    const float* __restrict__ W2lc, const float* __restrict__ W2rc,
    const float* __restrict__ W2rw, const float* __restrict__ W2lw,
    const float* __restrict__ b1c, const float* __restrict__ b1w,
    const float* __restrict__ b2c, const float* __restrict__ b2w,
    u16* __restrict__ wt1h, u16* __restrict__ wt1l,
    u16* __restrict__ wt2h, u16* __restrict__ wt2l,
    float* __restrict__ b1s, float* __restrict__ b2s,
    int* __restrict__ gsizes) {
    int m = blockIdx.x, t = threadIdx.x;
    if (m == 0) {
        for (int e = t; e < 3 * NCB; e += 256) gsizes[e] = 0;
    }
    if (m < 5) {
        const float *A = nullptr, *B = nullptr;
        if (m == 0) A = W1lc;
        else if (m == 1) A = W1lr;
        else if (m == 2) { A = W1rc; B = W1rw; }
        else if (m == 3) A = W1lw;
        else A = W1rr;
        for (int e = t; e < 2048; e += 256) {
            int k = e >> 5, n = e & 31;
            float v = A[e] + (B ? B[e] : 0.f);
            u16 h = f2bf(v);
            u16 lw = f2bf(v - bf2f(h));
            wt1h[m * 2048 + n * 64 + k] = h;
            wt1l[m * 2048 + n * 64 + k] = lw;
        }
        if (m == 2 && t < HH) b1s[t] = b1c[t] + b1w[t];
    } else {
        int mm = m - 5;
        const float *A = nullptr, *B = nullptr;
        if (mm == 0) A = W2lc;
        else if (mm == 1) { A = W2rc; B = W2rw; }
        else A = W2lw;
        for (int e = t; e < 1024; e += 256) {
            int k = e >> 5, n = e & 31;
            float v = A[e] + (B ? B[e] : 0.f);
            u16 h = f2bf(v);
            u16 lw = f2bf(v - bf2f(h));
            wt2h[mm * 1024 + n * 32 + k] = h;
            wt2l[mm * 1024 + n * 32 + k] = lw;
        }
        if (mm == 1 && t < HH) b2s[t] = b2c[t] + b2w[t];
    }
}

// ---------- L1 gather-aggregate (dual-stream), writes RELU'd hb ----------
__global__ __launch_bounds__(256) void agg1_k(
    const u16* __restrict__ y_pc, const u16* __restrict__ y_aw,
    const u16* __restrict__ y_pr,
    const int* __restrict__ st_c, const int* __restrict__ bkt_c,
    const int* __restrict__ st_w, const int* __restrict__ bkt_w,
    const int* __restrict__ st_r, const int* __restrict__ bkt_r,
    u32* __restrict__ hb_p, u32* __restrict__ hb_a) {
    int t = threadIdx.x, g = t >> 4, lane = t & 15;
    if (blockIdx.x < NB_P16) {
        int row = blockIdx.x * 16 + g;
        u32 self = hb_p[(size_t)row * (HH / 2) + lane];   // prefetch before gathers
        int s0 = st_c[row], e0 = st_c[row + 1];           // sentinel-terminated
        int s1 = st_w[row], e1 = st_w[row + 1];
        float cx, cy, wx, wy;
        gseg_dual(y_pc, bkt_c, s0, e0, y_aw, bkt_w, s1, e1, lane, cx, cy, wx, wy);
        int d0 = e0 - s0, d1 = e1 - s1;
        float iv0 = 1.0f / (float)(d0 < 1 ? 1 : d0);
        float iv1 = 1.0f / (float)(d1 < 1 ? 1 : d1);
        float ax = fmaxf(cx * iv0 + wx * iv1 + lo_f(self), 0.f);   // relu here
        float ay = fmaxf(cy * iv0 + wy * iv1 + hi_f(self), 0.f);
        hb_p[(size_t)row * (HH / 2) + lane] = cvtpk(ax, ay);
    } else {
        int row = (blockIdx.x - NB_P16) * 16 + g;
        u32 self = hb_a[(size_t)row * (HH / 2) + lane];
        int s = st_r[row], e = st_r[row + 1];
        int mid = (s + e) >> 1;
        float ax0, ay0, ax1, ay1;
        gseg_dual(y_pr, bkt_r, s, mid, y_pr, bkt_r, mid, e, lane, ax0, ay0, ax1, ay1);
        int dg = e - s;
        float iv = 1.0f / (float)(dg < 1 ? 1 : dg);
        float ax = fmaxf((ax0 + ax1) * iv + lo_f(self), 0.f);      // relu here
        float ay = fmaxf((ay0 + ay1) * iv + hi_f(self), 0.f);
        hb_a[(size_t)row * (HH / 2) + lane] = cvtpk(ax, ay);
    }
}

// ---------- L2: gather relu'd hb means + full MFMA epilogue (t2 folded in) ----------
__global__ __launch_bounds__(256) void agg2_k(
    const u16* __restrict__ hb_p, const u16* __restrict__ hb_a,
    const int* __restrict__ st_c, const int* __restrict__ bkt_c,
    const int* __restrict__ st_w, const int* __restrict__ bkt_w,
    const u16* __restrict__ wt2h, const u16* __restrict__ wt2l,
    const float* __restrict__ b2s, float* __restrict__ out) {
    __shared__ float mcs[16][34];
    __shared__ float mws[16][34];
    __shared__ float cso[16][34];
    int t = threadIdx.x, g = t >> 4, lane = t & 15;
    int row0 = blockIdx.x * 16;
    int row = row0 + g;
    int s0 = st_c[row], e0 = st_c[row + 1];
    int s1 = st_w[row], e1 = st_w[row + 1];
    float cx, cy, wx, wy;
    gseg_dual(hb_p, bkt_c, s0, e0, hb_a, bkt_w, s1, e1, lane, cx, cy, wx, wy);
    int d0 = e0 - s0, d1 = e1 - s1;
    float iv0 = 1.0f / (float)(d0 < 1 ? 1 : d0);
    float iv1 = 1.0f / (float)(d1 < 1 ? 1 : d1);
    mcs[g][2 * lane] = cx * iv0;  mcs[g][2 * lane + 1] = cy * iv0;
    mws[g][2 * lane] = wx * iv1;  mws[g][2 * lane + 1] = wy * iv1;
    __syncthreads();
    if (t < 64) {
        int lm = t & 15, lk = t >> 4;
        bf16x8 as_ = *(const bf16x8*)(hb_p + (size_t)(row0 + lm) * HH + lk * 8);
        bf16x8 mch, mcl, mwh, mwl;
        {
            union { u32 u[4]; bf16x8 v; } H, L;
#pragma unroll
            for (int j = 0; j < 4; ++j) {
                float f0 = mcs[lm][lk * 8 + 2 * j];
                float f1 = mcs[lm][lk * 8 + 2 * j + 1];
                u32 u0 = __float_as_uint(f0), u1 = __float_as_uint(f1);
                u32 m0 = u0 & 0xffff0000u, m1 = u1 & 0xffff0000u;
                H.u[j] = (u0 >> 16) | m1;
                L.u[j] = cvtpk(f0 - __uint_as_float(m0), f1 - __uint_as_float(m1));
            }
            mch = H.v; mcl = L.v;
#pragma unroll
            for (int j = 0; j < 4; ++j) {
                float f0 = mws[lm][lk * 8 + 2 * j];
                float f1 = mws[lm][lk * 8 + 2 * j + 1];
                u32 u0 = __float_as_uint(f0), u1 = __float_as_uint(f1);
                u32 m0 = u0 & 0xffff0000u, m1 = u1 & 0xffff0000u;
                H.u[j] = (u0 >> 16) | m1;
                L.u[j] = cvtpk(f0 - __uint_as_float(m0), f1 - __uint_as_float(m1));
            }
            mwh = H.v; mwl = L.v;
        }
#pragma unroll
        for (int ct = 0; ct < 2; ++ct) {
            int boff = (ct * 16 + lm) * 32 + lk * 8;
            bf16x8 Bch = *(const bf16x8*)(wt2h + boff);
            bf16x8 Bcl = *(const bf16x8*)(wt2l + boff);
            bf16x8 Bsh = *(const bf16x8*)(wt2h + 1024 + boff);
            bf16x8 Bsl = *(const bf16x8*)(wt2l + 1024 + boff);
            bf16x8 Bwh = *(const bf16x8*)(wt2h + 2048 + boff);
            bf16x8 Bwl = *(const bf16x8*)(wt2l + 2048 + boff);
            float bb = b2s[ct * 16 + lm];
            f32x4 acc = {bb, bb, bb, bb};
            acc = __builtin_amdgcn_mfma_f32_16x16x32_bf16(as_, Bsh, acc, 0, 0, 0);
            acc = __builtin_amdgcn_mfma_f32_16x16x32_bf16(as_, Bsl, acc, 0, 0, 0);
            acc = __builtin_amdgcn_mfma_f32_16x16x32_bf16(mch, Bch, acc, 0, 0, 0);
            acc = __builtin_amdgcn_mfma_f32_16x16x32_bf16(mcl, Bch, acc, 0, 0, 0);
            acc = __builtin_amdgcn_mfma_f32_16x16x32_bf16(mch, Bcl, acc, 0, 0, 0);
            acc = __builtin_amdgcn_mfma_f32_16x16x32_bf16(mwh, Bwh, acc, 0, 0, 0);
            acc = __builtin_amdgcn_mfma_f32_16x16x32_bf16(mwl, Bwh, acc, 0, 0, 0);
            acc = __builtin_amdgcn_mfma_f32_16x16x32_bf16(mwh, Bwl, acc, 0, 0, 0);
#pragma unroll
            for (int r = 0; r < 4; ++r)
                cso[lk * 4 + r][ct * 16 + lm] = acc[r];
        }
    }
    __syncthreads();
    int r = t >> 4, c = (t & 15) * 2;
    *(float2*)(out + (size_t)(row0 + r) * HH + c) = make_float2(cso[r][c], cso[r][c + 1]);
}

extern "C" void kernel_launch(void* const* d_in, const int* in_sizes, int n_in,
                              void* d_out, int out_size, void* d_ws, size_t ws_size,
                              hipStream_t stream) {
    const float* x_p  = (const float*)d_in[0];
    const float* x_a  = (const float*)d_in[1];
    const int* c_src  = (const int*)d_in[2];
    const int* c_dst  = (const int*)d_in[3];
    const int* w_src  = (const int*)d_in[4];
    const int* w_dst  = (const int*)d_in[5];
    const int* r_src  = (const int*)d_in[6];
    const int* r_dst  = (const int*)d_in[7];
    const float* W1l_c = (const float*)d_in[8];
    const float* W1r_c = (const float*)d_in[9];
    const float* b1_c  = (const float*)d_in[10];
    const float* W1l_w = (const float*)d_in[11];
    const float* W1r_w = (const float*)d_in[12];
    const float* b1_w  = (const float*)d_in[13];
    const float* W1l_r = (const float*)d_in[14];
    const float* W1r_r = (const float*)d_in[15];
    const float* b1_r  = (const float*)d_in[16];
    const float* W2l_c = (const float*)d_in[17];
    const float* W2r_c = (const float*)d_in[18];
    const float* b2_c  = (const float*)d_in[19];
    const float* W2l_w = (const float*)d_in[20];
    const float* W2r_w = (const float*)d_in[21];
    const float* b2_w  = (const float*)d_in[22];

    // ---- workspace layout (st arrays +1 sentinel each) ----
    int* gsizes = (int*)d_ws;
    int* bases  = gsizes + 3 * NCB;
    int* gcur   = bases + 3 * NCB;
    int* st_c   = gcur + 3 * NCB;
    int* st_w   = st_c + N_P + 1;
    int* st_r   = st_w + N_P + 1;
    int* bkt_c  = st_r + N_A + 1;
    int* bkt_w  = bkt_c + NE;
    int* bkt_r  = bkt_w + NE;
    u16* wt1h  = (u16*)(bkt_r + NE);      // 5*2048
    u16* wt1l  = wt1h + 5 * 2048;
    u16* wt2h  = wt1l + 5 * 2048;         // 3*1024
    u16* wt2l  = wt2h + 3 * 1024;
    float* b1s = (float*)(wt2l + 3 * 1024);
    float* b2s = b1s + HH;
    u16* hb_p  = (u16*)(b2s + HH);
    u16* hb_a  = hb_p + (size_t)N_P * HH;
    u16* y_pc  = hb_a + (size_t)N_A * HH;
    u16* y_pr  = y_pc + (size_t)N_P * HH;
    u16* y_aw  = y_pr + (size_t)N_P * HH;
    float* tail = (float*)(y_aw + (size_t)N_A * HH);   // pr staging region
    u32* pr_c  = (u32*)tail;
    u32* pr_w  = pr_c + NE;
    u32* pr_r  = pr_w + NE;
    float* outp = (float*)d_out;

    const size_t need = ((uintptr_t)(pr_r + NE)) - (uintptr_t)d_ws;
    if (ws_size < need) return;  // fail loudly, not OOB

    prep_w_k<<<8, 256, 0, stream>>>(W1l_c, W1l_r, W1r_c, W1r_w, W1l_w, W1r_r,
                                    W2l_c, W2r_c, W2r_w, W2l_w,
                                    b1_c, b1_w, b2_c, b2_w,
                                    wt1h, wt1l, wt2h, wt2l, b1s, b2s, gsizes);
    p1_hist_k<<<dim3(NB4K, 3), 256, 0, stream>>>(c_dst, w_dst, r_dst, gsizes);
    p2_scan_k<<<3, 256, 0, stream>>>(gsizes, bases, gcur, st_c, st_w, st_r);
    p3t1_k<<<NB4K3 + NBP + NBA, 256, 0, stream>>>(
        c_src, c_dst, w_src, w_dst, r_src, r_dst, gcur, pr_c, pr_w, pr_r,
        x_p, x_a, wt1h, wt1l, b1s, b1_r, y_pc, y_pr, y_aw, hb_p, hb_a);
    p4_sort_k<<<dim3(NCB, 3), 256, 0, stream>>>(bases, gsizes, pr_c, pr_w, pr_r,
                                                bkt_c, bkt_w, bkt_r, st_c, st_w, st_r);
    agg1_k<<<NB_P16 + NB_A16, 256, 0, stream>>>(y_pc, y_aw, y_pr,
                                                st_c, bkt_c, st_w, bkt_w, st_r, bkt_r,
                                                (u32*)hb_p, (u32*)hb_a);
    agg2_k<<<NB_P16, 256, 0, stream>>>(hb_p, hb_a, st_c, bkt_c, st_w, bkt_w,
                                       wt2h, wt2l, b2s, outp);
}